// Round 13
// baseline (56.085 us; speedup 1.0000x reference)
//
#include <hip/hip_runtime.h>
#include <math.h>

// NTM memory step: B=32, H=4, N=8192, D=64, S=3
#define Bc 32
#define Hc 4
#define Nc 8192
#define Dc 64
#define EPSc 1e-10f

#define T1ROWS 256
#define NT1 (Nc / T1ROWS)    // 32 tiles for K1
#define T2ROWS 256
#define NT2 (Nc / T2ROWS)    // 32 tiles for K2
#define T3ROWS 128
#define NT3 (Nc / T3ROWS)    // 64 tiles for K3

// ---------------- K1: t = exp(beta*cos), per-tile partial sums ----------------
// R9 structure (row-per-thread, XOR-swizzled LDS halves) + software pipeline:
// phase-B global loads are issued into registers BEFORE phase-A compute, so
// HBM latency hides under the FMAs. tbuf written interleaved float4 [n][h].
__global__ __launch_bounds__(256) void k_scores(
    const float* __restrict__ mem, const float* __restrict__ kk,
    const float* __restrict__ beta,
    float4* __restrict__ tbuf4, float* __restrict__ z1p)
{
    const int b = blockIdx.y, tile = blockIdx.x, tid = threadIdx.x;
    const int wave = tid >> 6, lane = tid & 63;
    const int n0 = tile * T1ROWS;

    __shared__ __align__(16) float ks[Hc][Dc];   // beta * k / (||k||+eps)
    __shared__ float4 lrow4[T1ROWS * 8];         // 32 KB, swizzled half-rows
    __shared__ float wsum[4][Hc];

    {   // wave w builds scaled key for head w (lane = dim)
        float kv = kk[(b * Hc + wave) * Dc + lane];
        float ss = kv * kv;
        #pragma unroll
        for (int off = 32; off; off >>= 1) ss += __shfl_xor(ss, off);
        float scale = beta[b * Hc + wave] / (sqrtf(ss) + EPSc);
        ks[wave][lane] = kv * scale;
    }

    const float4* mem4 = reinterpret_cast<const float4*>(mem)
                         + ((size_t)b * Nc + n0) * 16;

    // phase A (cols 0-31): load to regs, write LDS
    float4 rA[8];
    #pragma unroll
    for (int k = 0; k < 8; ++k) {
        const int f = k * 256 + tid;
        const int r = f >> 3, sp = f & 7, c = sp ^ (r & 7);
        rA[k] = mem4[r * 16 + c];
    }
    #pragma unroll
    for (int k = 0; k < 8; ++k) lrow4[k * 256 + tid] = rA[k];
    __syncthreads();                             // B1: keys + phase A visible

    // issue phase B (cols 32-63) loads NOW — they fly under phase-A compute
    float4 rB[8];
    #pragma unroll
    for (int k = 0; k < 8; ++k) {
        const int f = k * 256 + tid;
        const int r = f >> 3, sp = f & 7, c = sp ^ (r & 7);
        rB[k] = mem4[r * 16 + 8 + c];
    }

    float ssacc = 0.f;
    float dot[Hc] = {0.f, 0.f, 0.f, 0.f};
    const float4* ks4 = reinterpret_cast<const float4*>(&ks[0][0]);

    #pragma unroll
    for (int c = 0; c < 8; ++c) {                // compute phase A
        const float4 v = lrow4[tid * 8 + (c ^ (tid & 7))];
        ssacc = fmaf(v.x, v.x, ssacc); ssacc = fmaf(v.y, v.y, ssacc);
        ssacc = fmaf(v.z, v.z, ssacc); ssacc = fmaf(v.w, v.w, ssacc);
        #pragma unroll
        for (int h = 0; h < Hc; ++h) {
            const float4 kf = ks4[h * 16 + c];   // wave-uniform broadcast
            dot[h] = fmaf(v.x, kf.x, dot[h]);
            dot[h] = fmaf(v.y, kf.y, dot[h]);
            dot[h] = fmaf(v.z, kf.z, dot[h]);
            dot[h] = fmaf(v.w, kf.w, dot[h]);
        }
    }
    __syncthreads();                             // B2: WAR on lrow4
    #pragma unroll
    for (int k = 0; k < 8; ++k) lrow4[k * 256 + tid] = rB[k];
    __syncthreads();                             // B3: phase B visible

    #pragma unroll
    for (int c = 0; c < 8; ++c) {                // compute phase B
        const float4 v = lrow4[tid * 8 + (c ^ (tid & 7))];
        ssacc = fmaf(v.x, v.x, ssacc); ssacc = fmaf(v.y, v.y, ssacc);
        ssacc = fmaf(v.z, v.z, ssacc); ssacc = fmaf(v.w, v.w, ssacc);
        #pragma unroll
        for (int h = 0; h < Hc; ++h) {
            const float4 kf = ks4[h * 16 + 8 + c];
            dot[h] = fmaf(v.x, kf.x, dot[h]);
            dot[h] = fmaf(v.y, kf.y, dot[h]);
            dot[h] = fmaf(v.z, kf.z, dot[h]);
            dot[h] = fmaf(v.w, kf.w, dot[h]);
        }
    }

    const float inv = 1.0f / (sqrtf(ssacc) + EPSc);
    float4 tq;
    float* tqp = reinterpret_cast<float*>(&tq);
    float psum[Hc];
    #pragma unroll
    for (int h = 0; h < Hc; ++h) {
        tqp[h] = __expf(dot[h] * inv);           // |beta*cos| < 5: exp safe
        psum[h] = tqp[h];
    }
    tbuf4[(size_t)b * Nc + n0 + tid] = tq;       // one coalesced 16B store

    #pragma unroll
    for (int h = 0; h < Hc; ++h) {
        #pragma unroll
        for (int off = 32; off; off >>= 1) psum[h] += __shfl_xor(psum[h], off);
        if (lane == 0) wsum[wave][h] = psum[h];
    }
    __syncthreads();
    if (tid < Hc)
        z1p[(b * Hc + tid) * NT1 + tile] =
            wsum[0][tid] + wsum[1][tid] + wsum[2][tid] + wsum[3][tid];
}

// ------- K2: wg = g*wc+(1-g)*pw; 3-tap circular shift; sharpen -------
// Thread = one row n, all 4 heads. ALL global loads issued before the Z1
// reduction so they fly under it. tbuf read as float4 (3 loads), wgbuf
// written interleaved float4.
__global__ __launch_bounds__(256) void k_shift(
    const float4* __restrict__ tbuf4, const float* __restrict__ z1p,
    const float* __restrict__ pw, const float* __restrict__ g,
    const float* __restrict__ s, const float* __restrict__ gamma,
    float4* __restrict__ wgbuf4, float* __restrict__ z2p,
    float* __restrict__ out)
{
    const int b = blockIdx.y, tile = blockIdx.x, tid = threadIdx.x;
    const int wave = tid >> 6, lane = tid & 63;
    const int n = tile * T2ROWS + tid;

    if (tile == 0) out[b * 256 + tid] = 0.f;     // zero output for K3 atomics

    const int nm = (n + Nc - 1) & (Nc - 1);
    const int np = (n + 1) & (Nc - 1);

    // ---- issue ALL global loads first ----
    const float4 tmv = tbuf4[(size_t)b * Nc + nm];
    const float4 tcv = tbuf4[(size_t)b * Nc + n];
    const float4 tpv = tbuf4[(size_t)b * Nc + np];
    float pwm[Hc], pwc[Hc], pwp[Hc];
    #pragma unroll
    for (int h = 0; h < Hc; ++h) {
        const int base = (b * Hc + h) * Nc;
        pwm[h] = pw[base + nm];
        pwc[h] = pw[base + n];
        pwp[h] = pw[base + np];
    }

    __shared__ float invZ[Hc];
    __shared__ float gS[Hc], gmS[Hc], sS[Hc][3];
    __shared__ float wsum[4][Hc];

    {   // wave w reduces Z1 for head w (NT1=32 partials) — overlaps loads
        float v = (lane < NT1) ? z1p[(b * Hc + wave) * NT1 + lane] : 0.f;
        #pragma unroll
        for (int off = 32; off; off >>= 1) v += __shfl_xor(v, off);
        if (lane == 0) invZ[wave] = 1.0f / v;
    }
    if (tid < Hc)     { gS[tid] = g[b * Hc + tid]; gmS[tid] = gamma[b * Hc + tid]; }
    if (tid < Hc * 3) sS[tid / 3][tid % 3] = s[b * Hc * 3 + tid];
    __syncthreads();

    const float* tmf = reinterpret_cast<const float*>(&tmv);
    const float* tcf = reinterpret_cast<const float*>(&tcv);
    const float* tpf = reinterpret_cast<const float*>(&tpv);

    float4 wq;
    float* wqp = reinterpret_cast<float*>(&wq);
    float psum[Hc];
    #pragma unroll
    for (int h = 0; h < Hc; ++h) {
        const float gh = gS[h], omg = 1.0f - gS[h], iz = invZ[h];
        const float wg_m = gh * tmf[h] * iz + omg * pwm[h];
        const float wg_c = gh * tcf[h] * iz + omg * pwc[h];
        const float wg_p = gh * tpf[h] * iz + omg * pwp[h];
        // ws[i] = s0*wg[i+1] + s1*wg[i] + s2*wg[i-1]  (roll semantics)
        const float wsv = sS[h][0] * wg_p + sS[h][1] * wg_c + sS[h][2] * wg_m;
        wqp[h] = __powf(wsv, gmS[h]);
        psum[h] = wqp[h];
    }
    wgbuf4[(size_t)b * Nc + n] = wq;             // coalesced 16B store

    #pragma unroll
    for (int h = 0; h < Hc; ++h) {
        #pragma unroll
        for (int off = 32; off; off >>= 1) psum[h] += __shfl_xor(psum[h], off);
        if (lane == 0) wsum[wave][h] = psum[h];
    }
    __syncthreads();
    if (tid < Hc)
        z2p[(b * Hc + tid) * NT2 + tile] =
            wsum[0][tid] + wsum[1][tid] + wsum[2][tid] + wsum[3][tid];
}

// --- K3: sequential 4-head erase/add per row + read partials -> atomic out ---
// e4/a4 loads hoisted above the Z2 reduction; main loop fully unrolled so all
// 16 loads issue up front.
__global__ __launch_bounds__(256) void k_update(
    const float* __restrict__ mem, const float4* __restrict__ wgbuf4,
    const float* __restrict__ z2p, const float* __restrict__ erase,
    const float* __restrict__ add, float* __restrict__ out)
{
    const int b = blockIdx.y, tile = blockIdx.x, tid = threadIdx.x;
    const int part = tid & 15;     // which float4 of the row (d = part*4..+3)
    const int rw   = tid >> 4;     // row-group 0..15

    // ---- independent loads first ----
    float4 e4[Hc], a4[Hc];
    #pragma unroll
    for (int h = 0; h < Hc; ++h) {
        e4[h] = *reinterpret_cast<const float4*>(erase + (b * Hc + h) * Dc + part * 4);
        a4[h] = *reinterpret_cast<const float4*>(add   + (b * Hc + h) * Dc + part * 4);
    }

    __shared__ float invZ2[Hc];
    {   // wave w reduces Z2 for head w (NT2=32 partials)
        const int wave = tid >> 6, lane = tid & 63;
        float v = (lane < NT2) ? z2p[(b * Hc + wave) * NT2 + lane] : 0.f;
        #pragma unroll
        for (int off = 32; off; off >>= 1) v += __shfl_xor(v, off);
        if (lane == 0) invZ2[wave] = 1.0f / v;
    }
    __syncthreads();

    float iz[Hc];
    #pragma unroll
    for (int h = 0; h < Hc; ++h) iz[h] = invZ2[h];

    float4 r4[Hc];
    #pragma unroll
    for (int h = 0; h < Hc; ++h) r4[h] = make_float4(0.f, 0.f, 0.f, 0.f);

    const int n0 = tile * T3ROWS;
    #pragma unroll
    for (int i = 0; i < T3ROWS / 16; ++i) {      // 8 iters, fully unrolled
        const int n = n0 + i * 16 + rw;
        const float4 m0 = *reinterpret_cast<const float4*>(
            mem + ((size_t)b * Nc + n) * Dc + part * 4);
        const float4 wv = wgbuf4[(size_t)b * Nc + n];   // broadcast per 16 lanes
        float w[Hc];
        w[0] = wv.x * iz[0]; w[1] = wv.y * iz[1];
        w[2] = wv.z * iz[2]; w[3] = wv.w * iz[3];
        float4 m4 = m0;
        #pragma unroll
        for (int h = 0; h < Hc; ++h) {           // sequential head writes
            m4.x = m4.x * (1.0f - w[h] * e4[h].x) + w[h] * a4[h].x;
            m4.y = m4.y * (1.0f - w[h] * e4[h].y) + w[h] * a4[h].y;
            m4.z = m4.z * (1.0f - w[h] * e4[h].z) + w[h] * a4[h].z;
            m4.w = m4.w * (1.0f - w[h] * e4[h].w) + w[h] * a4[h].w;
        }
        #pragma unroll
        for (int h = 0; h < Hc; ++h) {           // all heads read final memory
            r4[h].x = fmaf(w[h], m4.x, r4[h].x);
            r4[h].y = fmaf(w[h], m4.y, r4[h].y);
            r4[h].z = fmaf(w[h], m4.z, r4[h].z);
            r4[h].w = fmaf(w[h], m4.w, r4[h].w);
        }
    }

    __shared__ float4 acc[16][Hc][16];           // 16 KiB
    #pragma unroll
    for (int h = 0; h < Hc; ++h) acc[rw][h][part] = r4[h];
    __syncthreads();

    // reduce over 16 row-groups: thread -> (h = tid>>6, d = tid&63)
    const int h = tid >> 6, d = tid & 63;
    float sum = 0.f;
    #pragma unroll
    for (int r2 = 0; r2 < 16; ++r2)
        sum += reinterpret_cast<const float*>(&acc[r2][h][d >> 2])[d & 3];
    atomicAdd(out + b * 256 + h * 64 + d, sum);
}

extern "C" void kernel_launch(void* const* d_in, const int* in_sizes, int n_in,
                              void* d_out, int out_size, void* d_ws, size_t ws_size,
                              hipStream_t stream) {
    const float* mem   = (const float*)d_in[0];
    const float* kk    = (const float*)d_in[1];
    const float* beta  = (const float*)d_in[2];
    const float* pw    = (const float*)d_in[3];
    const float* g     = (const float*)d_in[4];
    const float* s     = (const float*)d_in[5];
    const float* gamma = (const float*)d_in[6];
    const float* erase = (const float*)d_in[7];
    const float* add   = (const float*)d_in[8];
    float* out = (float*)d_out;

    float*  ws     = (float*)d_ws;
    float4* tbuf4  = (float4*)ws;                         // B*N float4 = 4 MB
    float4* wgbuf4 = tbuf4 + (size_t)Bc * Nc;             // B*N float4 = 4 MB
    float*  z1p    = (float*)(wgbuf4 + (size_t)Bc * Nc);  // B*H*NT1 = 4096
    float*  z2p    = z1p + (size_t)Bc * Hc * NT1;         // B*H*NT2 = 4096

    k_scores<<<dim3(NT1, Bc), 256, 0, stream>>>(mem, kk, beta, tbuf4, z1p);
    k_shift <<<dim3(NT2, Bc), 256, 0, stream>>>(tbuf4, z1p, pw, g, s, gamma,
                                                wgbuf4, z2p, out);
    k_update<<<dim3(NT3, Bc), 256, 0, stream>>>(mem, wgbuf4, z2p, erase, add, out);
}

// Round 14
// 41.138 us; speedup vs baseline: 1.3634x; 1.3634x over previous
//
#include <hip/hip_runtime.h>
#include <math.h>

// NTM memory step: B=32, H=4, N=8192, D=64, S=3
#define Bc 32
#define Hc 4
#define Nc 8192
#define Dc 64
#define EPSc 1e-10f

#define T1ROWS 256
#define NT1 (Nc / T1ROWS)    // 32 tiles for K1
#define T2ROWS 256
#define NT2 (Nc / T2ROWS)    // 32 tiles for K2
#define T3ROWS 128
#define NT3 (Nc / T3ROWS)    // 64 tiles for K3

// ---------------- K1: t = exp(beta*cos), per-tile partial sums ----------------
// (R9 version — measured best.) Row-per-thread compute; rows staged via LDS in
// two 32-col halves (coalesced 128B global segments); row reads XOR-swizzled
// ds_read_b128 (conflict-free); key reads wave-uniform b128 broadcasts.
__global__ __launch_bounds__(256) void k_scores(
    const float* __restrict__ mem, const float* __restrict__ kk,
    const float* __restrict__ beta,
    float* __restrict__ tbuf, float* __restrict__ z1p)
{
    const int b = blockIdx.y, tile = blockIdx.x, tid = threadIdx.x;
    const int wave = tid >> 6, lane = tid & 63;
    const int n0 = tile * T1ROWS;

    __shared__ __align__(16) float ks[Hc][Dc];   // beta * k / (||k||+eps)
    __shared__ float4 lrow4[T1ROWS * 8];         // 32 KB: [row][slot] swizzled
    __shared__ float wsum[4][Hc];

    {   // wave w builds scaled key for head w (lane = dim)
        float kv = kk[(b * Hc + wave) * Dc + lane];
        float ss = kv * kv;
        #pragma unroll
        for (int off = 32; off; off >>= 1) ss += __shfl_xor(ss, off);
        float scale = beta[b * Hc + wave] / (sqrtf(ss) + EPSc);
        ks[wave][lane] = kv * scale;
    }
    __syncthreads();

    const float4* mem4 = reinterpret_cast<const float4*>(mem) + ((size_t)b * Nc + n0) * 16;

    float ssacc = 0.f;
    float dot[Hc] = {0.f, 0.f, 0.f, 0.f};

    #pragma unroll
    for (int hf = 0; hf < 2; ++hf) {             // column halves: 0-31, 32-63
        if (hf) __syncthreads();                 // WAR on lrow4 reuse

        // stage: LDS[r][sp] <- global col-block (sp ^ (r&7)) of row r.
        // Linear LDS writes; global perm stays within each 256B row: coalesced.
        #pragma unroll
        for (int k = 0; k < 8; ++k) {
            const int f = k * 256 + tid;
            const int r = f >> 3, sp = f & 7;
            const int c = sp ^ (r & 7);
            lrow4[f] = mem4[r * 16 + hf * 8 + c];
        }
        __syncthreads();

        // compute: thread = row tid; keys via wave-uniform broadcast reads
        const float4* ks4 = reinterpret_cast<const float4*>(&ks[0][0]);
        #pragma unroll
        for (int c = 0; c < 8; ++c) {
            const float4 v = lrow4[tid * 8 + (c ^ (tid & 7))];
            ssacc = fmaf(v.x, v.x, ssacc); ssacc = fmaf(v.y, v.y, ssacc);
            ssacc = fmaf(v.z, v.z, ssacc); ssacc = fmaf(v.w, v.w, ssacc);
            #pragma unroll
            for (int h = 0; h < Hc; ++h) {
                const float4 kf = ks4[h * 16 + hf * 8 + c];  // broadcast b128
                dot[h] = fmaf(v.x, kf.x, dot[h]);
                dot[h] = fmaf(v.y, kf.y, dot[h]);
                dot[h] = fmaf(v.z, kf.z, dot[h]);
                dot[h] = fmaf(v.w, kf.w, dot[h]);
            }
        }
    }

    const float inv = 1.0f / (sqrtf(ssacc) + EPSc);
    float psum[Hc];
    #pragma unroll
    for (int h = 0; h < Hc; ++h) {
        const float tv = __expf(dot[h] * inv);   // |beta*cos| < 5: exp safe
        tbuf[(b * Hc + h) * Nc + n0 + tid] = tv; // coalesced per head
        psum[h] = tv;
    }

    #pragma unroll
    for (int h = 0; h < Hc; ++h) {
        #pragma unroll
        for (int off = 32; off; off >>= 1) psum[h] += __shfl_xor(psum[h], off);
        if (lane == 0) wsum[wave][h] = psum[h];
    }
    __syncthreads();
    if (tid < Hc)
        z1p[(b * Hc + tid) * NT1 + tile] =
            wsum[0][tid] + wsum[1][tid] + wsum[2][tid] + wsum[3][tid];
}

// ------- K2: wg = g*wc+(1-g)*pw; circular 3-tap shift; sharpen; partials -------
// grid (NT2, B), block 256. Wave w = head w, lane handles 4 consecutive rows.
// Block (0,b) also zeroes d_out[b] (K3 atomically accumulates into it).
__global__ __launch_bounds__(256) void k_shift(
    const float* __restrict__ tbuf, const float* __restrict__ z1p,
    const float* __restrict__ pw, const float* __restrict__ g,
    const float* __restrict__ s, const float* __restrict__ gamma,
    float* __restrict__ wgbuf, float* __restrict__ z2p,
    float* __restrict__ out)
{
    const int b = blockIdx.y, tile = blockIdx.x, tid = threadIdx.x;
    const int h = tid >> 6, lane = tid & 63;

    if (tile == 0) out[b * 256 + tid] = 0.f;     // zero output for K3 atomics

    // reduce Z1 partials for this wave's head (NT1=32)
    float v = (lane < NT1) ? z1p[(b * Hc + h) * NT1 + lane] : 0.f;
    #pragma unroll
    for (int off = 32; off; off >>= 1) v += __shfl_xor(v, off);
    const float invZ1 = __shfl(1.0f / v, 0);

    const float gh  = g[b * Hc + h];
    const float gmh = gamma[b * Hc + h];
    const float s0 = s[(b * Hc + h) * 3 + 0];
    const float s1 = s[(b * Hc + h) * 3 + 1];
    const float s2 = s[(b * Hc + h) * 3 + 2];
    const float omg = 1.0f - gh;

    const int n0   = tile * T2ROWS + lane * 4;
    const int base = (b * Hc + h) * Nc;
    const int nm = (n0 == 0) ? (Nc - 1) : (n0 - 1);
    const int np = (n0 + 4 == Nc) ? 0 : (n0 + 4);

    const float4 t4  = *reinterpret_cast<const float4*>(tbuf + base + n0);
    const float4 p4  = *reinterpret_cast<const float4*>(pw   + base + n0);
    const float  tm = tbuf[base + nm], pm = pw[base + nm];
    const float  tp = tbuf[base + np], pp = pw[base + np];

    const float wgm1 = gh * tm   * invZ1 + omg * pm;
    const float wg0  = gh * t4.x * invZ1 + omg * p4.x;
    const float wg1  = gh * t4.y * invZ1 + omg * p4.y;
    const float wg2  = gh * t4.z * invZ1 + omg * p4.z;
    const float wg3  = gh * t4.w * invZ1 + omg * p4.w;
    const float wg4  = gh * tp   * invZ1 + omg * pp;

    // ws[i] = s0*wg[i+1] + s1*wg[i] + s2*wg[i-1]  (roll semantics)
    float4 wgam;
    wgam.x = __powf(s0 * wg1 + s1 * wg0 + s2 * wgm1, gmh);
    wgam.y = __powf(s0 * wg2 + s1 * wg1 + s2 * wg0,  gmh);
    wgam.z = __powf(s0 * wg3 + s1 * wg2 + s2 * wg1,  gmh);
    wgam.w = __powf(s0 * wg4 + s1 * wg3 + s2 * wg2,  gmh);
    *reinterpret_cast<float4*>(wgbuf + base + n0) = wgam;

    float pv = wgam.x + wgam.y + wgam.z + wgam.w;
    #pragma unroll
    for (int off = 32; off; off >>= 1) pv += __shfl_xor(pv, off);
    if (lane == 0) z2p[(b * Hc + h) * NT2 + tile] = pv;
}

// --- K3: sequential 4-head erase/add per row + read partials -> atomic out ---
// grid (NT3, B), block 256 = 16 row-groups x 16 float4-parts. float4 loads.
__global__ __launch_bounds__(256) void k_update(
    const float* __restrict__ mem, const float* __restrict__ wgbuf,
    const float* __restrict__ z2p, const float* __restrict__ erase,
    const float* __restrict__ add, float* __restrict__ out)
{
    const int b = blockIdx.y, tile = blockIdx.x, tid = threadIdx.x;
    const int part = tid & 15;     // which float4 of the row (d = part*4..+3)
    const int rw   = tid >> 4;     // row-group 0..15

    __shared__ float invZ2[Hc];
    {   // wave w reduces Z2 for head w (NT2=32 partials)
        const int wave = tid >> 6, lane = tid & 63;
        float v = (lane < NT2) ? z2p[(b * Hc + wave) * NT2 + lane] : 0.f;
        #pragma unroll
        for (int off = 32; off; off >>= 1) v += __shfl_xor(v, off);
        if (lane == 0) invZ2[wave] = 1.0f / v;
    }
    __syncthreads();

    float4 e4[Hc], a4[Hc];
    float iz[Hc];
    #pragma unroll
    for (int h = 0; h < Hc; ++h) {
        e4[h] = *reinterpret_cast<const float4*>(erase + (b * Hc + h) * Dc + part * 4);
        a4[h] = *reinterpret_cast<const float4*>(add   + (b * Hc + h) * Dc + part * 4);
        iz[h] = invZ2[h];
    }

    float4 r4[Hc];
    #pragma unroll
    for (int h = 0; h < Hc; ++h) r4[h] = make_float4(0.f, 0.f, 0.f, 0.f);

    const int n0 = tile * T3ROWS;
    #pragma unroll 4
    for (int i = 0; i < T3ROWS / 16; ++i) {      // 8 iters, 16 rows each
        const int n = n0 + i * 16 + rw;
        float4 m4 = *reinterpret_cast<const float4*>(
            mem + ((size_t)b * Nc + n) * Dc + part * 4);
        float w[Hc];
        #pragma unroll
        for (int h = 0; h < Hc; ++h)
            w[h] = wgbuf[(b * Hc + h) * Nc + n] * iz[h];
        #pragma unroll
        for (int h = 0; h < Hc; ++h) {           // sequential head writes
            m4.x = m4.x * (1.0f - w[h] * e4[h].x) + w[h] * a4[h].x;
            m4.y = m4.y * (1.0f - w[h] * e4[h].y) + w[h] * a4[h].y;
            m4.z = m4.z * (1.0f - w[h] * e4[h].z) + w[h] * a4[h].z;
            m4.w = m4.w * (1.0f - w[h] * e4[h].w) + w[h] * a4[h].w;
        }
        #pragma unroll
        for (int h = 0; h < Hc; ++h) {           // all heads read final memory
            r4[h].x = fmaf(w[h], m4.x, r4[h].x);
            r4[h].y = fmaf(w[h], m4.y, r4[h].y);
            r4[h].z = fmaf(w[h], m4.z, r4[h].z);
            r4[h].w = fmaf(w[h], m4.w, r4[h].w);
        }
    }

    __shared__ float4 acc[16][Hc][16];           // 16 KiB
    #pragma unroll
    for (int h = 0; h < Hc; ++h) acc[rw][h][part] = r4[h];
    __syncthreads();

    // reduce over 16 row-groups: thread -> (h = tid>>6, d = tid&63)
    const int h = tid >> 6, d = tid & 63;
    float sum = 0.f;
    #pragma unroll
    for (int r2 = 0; r2 < 16; ++r2)
        sum += reinterpret_cast<const float*>(&acc[r2][h][d >> 2])[d & 3];
    atomicAdd(out + b * 256 + h * 64 + d, sum);
}

extern "C" void kernel_launch(void* const* d_in, const int* in_sizes, int n_in,
                              void* d_out, int out_size, void* d_ws, size_t ws_size,
                              hipStream_t stream) {
    const float* mem   = (const float*)d_in[0];
    const float* kk    = (const float*)d_in[1];
    const float* beta  = (const float*)d_in[2];
    const float* pw    = (const float*)d_in[3];
    const float* g     = (const float*)d_in[4];
    const float* s     = (const float*)d_in[5];
    const float* gamma = (const float*)d_in[6];
    const float* erase = (const float*)d_in[7];
    const float* add   = (const float*)d_in[8];
    float* out = (float*)d_out;

    float* ws    = (float*)d_ws;
    float* tbuf  = ws;                           // B*H*N   = 1048576 floats
    float* wgbuf = tbuf + (size_t)Bc*Hc*Nc;      // 1048576
    float* z1p   = wgbuf + (size_t)Bc*Hc*Nc;     // B*H*NT1 = 4096
    float* z2p   = z1p + (size_t)Bc*Hc*NT1;      // B*H*NT2 = 4096

    k_scores<<<dim3(NT1, Bc), 256, 0, stream>>>(mem, kk, beta, tbuf, z1p);
    k_shift <<<dim3(NT2, Bc), 256, 0, stream>>>(tbuf, z1p, pw, g, s, gamma,
                                                wgbuf, z2p, out);
    k_update<<<dim3(NT3, Bc), 256, 0, stream>>>(mem, wgbuf, z2p, erase, add, out);
}